// Round 1
// baseline (115.626 us; speedup 1.0000x reference)
//
#include <hip/hip_runtime.h>
#include <math.h>

#define NA   1024     // num agents
#define HD   128      // hidden dim
#define GG   16       // G*G cells
#define PD   128      // pool (output) dim
#define FAN  2048     // GG*HD
#define NSPLIT 8      // split-K factor
#define KCHUNK 256    // FAN / NSPLIT
#define BK   64
#define BM   32
#define BN   128

// ---------------- Kernel 1: social pooling ----------------
// one block per agent, 256 threads (4 waves)
__global__ __launch_bounds__(256) void pool_kernel(
    const float* __restrict__ pos,
    const float* __restrict__ hidden,
    float* __restrict__ pooled /* [NA][FAN] */)
{
    __shared__ unsigned char cellid[NA];
    __shared__ float pbuf[4 * GG * HD];   // 4 per-wave max buffers, 32 KiB

    const int i = blockIdx.x;
    const int t = threadIdx.x;
    const float px = pos[2 * i], py = pos[2 * i + 1];

    // Pass A: classify every j into a cell (255 = not a valid neighbor).
    // NaN/inf positions propagate into dx/dy and fail the <= compares,
    // matching the reference's finite-pos masking.
    for (int j = t; j < NA; j += 256) {
        float dx = pos[2 * j]     - px;
        float dy = pos[2 * j + 1] - py;
        bool inbox = (fabsf(dx) <= 1.0f) && (fabsf(dy) <= 1.0f) && (j != i);
        int gx = (int)floorf((dx + 1.0f) * 2.0f);   // (rel + NS/2)/cell, cell=0.5
        int gy = (int)floorf((dy + 1.0f) * 2.0f);
        gx = min(max(gx, 0), 3);
        gy = min(max(gy, 0), 3);
        cellid[j] = inbox ? (unsigned char)(gx * 4 + gy) : (unsigned char)255;
    }
    for (int k = t; k < 4 * GG * HD; k += 256) pbuf[k] = -INFINITY;
    __syncthreads();

    // Pass B: each wave scans its 256 j's; float2-wide running max in LDS.
    {
        const int w = t >> 6, lane = t & 63;
        const float2* __restrict__ hid2 = (const float2*)hidden;  // [NA][64]
        float2* pw = (float2*)(pbuf + w * GG * HD);               // [GG][64]
        const int j0 = w * 256;
        for (int j = j0; j < j0 + 256; ++j) {
            int c = cellid[j];             // uniform within the wave
            if (c == 255) continue;        // uniform branch -> execz skip
            float2 v  = hid2[j * 64 + lane];
            float2 cu = pw[c * 64 + lane];
            cu.x = fmaxf(cu.x, v.x);
            cu.y = fmaxf(cu.y, v.y);
            pw[c * 64 + lane] = cu;
        }
    }
    __syncthreads();

    // Merge the 4 wave buffers; empty cells (-inf) -> 0.
    float* outrow = pooled + (size_t)i * FAN;
    for (int k = t; k < FAN; k += 256) {
        float m = fmaxf(fmaxf(pbuf[k],        pbuf[2048 + k]),
                        fmaxf(pbuf[4096 + k], pbuf[6144 + k]));
        outrow[k] = (m == -INFINITY) ? 0.0f : m;
    }
}

// ---------------- Kernel 2: fp32 tiled GEMM with split-K ----------------
// C_partial[kc][i][p] = sum_{k in chunk kc} pooled[i][k] * W[p][k]
__global__ __launch_bounds__(256) void gemm_kernel(
    const float* __restrict__ A,   // [NA][FAN]
    const float* __restrict__ W,   // [PD][FAN]
    float* __restrict__ part)      // [NSPLIT][NA][PD]
{
    __shared__ float As[BK][BM + 1];  // [k][m], +1 pad kills store conflicts
    __shared__ float Bs[BK][BN];      // [k][p]

    const int mt = blockIdx.x;        // 0..31
    const int kc = blockIdx.y;        // 0..7
    const int t  = threadIdx.x;
    const int m0 = mt * BM;
    const int k0 = kc * KCHUNK;
    const int tn = t & 31, tm = t >> 5;   // tn: 0..31 (p/4), tm: 0..7 (m/4)

    float acc[4][4] = {};

    for (int kt = 0; kt < KCHUNK; kt += BK) {
        // stage A tile (32 rows x 64 k), transposed into As[k][m]
        {
            const int row = t >> 3;           // 0..31
            const int kk  = (t & 7) * 8;      // 0..56
            const float4* src = (const float4*)(A + (size_t)(m0 + row) * FAN + k0 + kt + kk);
            #pragma unroll
            for (int u = 0; u < 2; ++u) {
                float4 v = src[u];
                As[kk + 4 * u + 0][row] = v.x;
                As[kk + 4 * u + 1][row] = v.y;
                As[kk + 4 * u + 2][row] = v.z;
                As[kk + 4 * u + 3][row] = v.w;
            }
        }
        // stage B tile (128 rows x 64 k), transposed into Bs[k][p]
        {
            const int row = t >> 1;           // 0..127
            const int kk  = (t & 1) * 32;     // 0 or 32
            const float4* src = (const float4*)(W + (size_t)row * FAN + k0 + kt + kk);
            #pragma unroll
            for (int u = 0; u < 8; ++u) {
                float4 v = src[u];
                Bs[kk + 4 * u + 0][row] = v.x;
                Bs[kk + 4 * u + 1][row] = v.y;
                Bs[kk + 4 * u + 2][row] = v.z;
                Bs[kk + 4 * u + 3][row] = v.w;
            }
        }
        __syncthreads();

        #pragma unroll 8
        for (int kk = 0; kk < BK; ++kk) {
            float a0 = As[kk][tm * 4 + 0];
            float a1 = As[kk][tm * 4 + 1];
            float a2 = As[kk][tm * 4 + 2];
            float a3 = As[kk][tm * 4 + 3];
            float4 bv = *(const float4*)&Bs[kk][tn * 4];
            acc[0][0] = fmaf(a0, bv.x, acc[0][0]);
            acc[0][1] = fmaf(a0, bv.y, acc[0][1]);
            acc[0][2] = fmaf(a0, bv.z, acc[0][2]);
            acc[0][3] = fmaf(a0, bv.w, acc[0][3]);
            acc[1][0] = fmaf(a1, bv.x, acc[1][0]);
            acc[1][1] = fmaf(a1, bv.y, acc[1][1]);
            acc[1][2] = fmaf(a1, bv.z, acc[1][2]);
            acc[1][3] = fmaf(a1, bv.w, acc[1][3]);
            acc[2][0] = fmaf(a2, bv.x, acc[2][0]);
            acc[2][1] = fmaf(a2, bv.y, acc[2][1]);
            acc[2][2] = fmaf(a2, bv.z, acc[2][2]);
            acc[2][3] = fmaf(a2, bv.w, acc[2][3]);
            acc[3][0] = fmaf(a3, bv.x, acc[3][0]);
            acc[3][1] = fmaf(a3, bv.y, acc[3][1]);
            acc[3][2] = fmaf(a3, bv.z, acc[3][2]);
            acc[3][3] = fmaf(a3, bv.w, acc[3][3]);
        }
        __syncthreads();
    }

    #pragma unroll
    for (int mm = 0; mm < 4; ++mm) {
        float4 v = make_float4(acc[mm][0], acc[mm][1], acc[mm][2], acc[mm][3]);
        *(float4*)(part + ((size_t)kc * NA + m0 + tm * 4 + mm) * PD + tn * 4) = v;
    }
}

// ---------------- Kernel 3: reduce partials + bias + relu ----------------
__global__ __launch_bounds__(256) void finish_kernel(
    const float* __restrict__ part,
    const float* __restrict__ bias,
    float* __restrict__ out)
{
    const int g = blockIdx.x * 256 + threadIdx.x;  // 0..NA*PD-1
    float s = bias[g & (PD - 1)];
    #pragma unroll
    for (int c = 0; c < NSPLIT; ++c)
        s += part[(size_t)c * NA * PD + g];
    out[g] = fmaxf(s, 0.0f);
}

extern "C" void kernel_launch(void* const* d_in, const int* in_sizes, int n_in,
                              void* d_out, int out_size, void* d_ws, size_t ws_size,
                              hipStream_t stream)
{
    const float* pos    = (const float*)d_in[0];
    const float* hidden = (const float*)d_in[1];
    const float* W      = (const float*)d_in[2];
    const float* b      = (const float*)d_in[3];
    float* out = (float*)d_out;

    float* pooled = (float*)d_ws;                   // NA*FAN f32 = 8 MiB
    float* part   = pooled + (size_t)NA * FAN;      // NSPLIT*NA*PD f32 = 4 MiB

    pool_kernel<<<NA, 256, 0, stream>>>(pos, hidden, pooled);
    gemm_kernel<<<dim3(NA / BM, NSPLIT), 256, 0, stream>>>(pooled, W, part);
    finish_kernel<<<(NA * PD) / 256, 256, 0, stream>>>(part, b, out);
}

// Round 3
// 97.636 us; speedup vs baseline: 1.1843x; 1.1843x over previous
//
#include <hip/hip_runtime.h>
#include <math.h>

#define NA   1024     // num agents
#define HD   128      // hidden dim
#define GG   16       // G*G cells
#define PD   128      // pool (output) dim
#define FAN  2048     // GG*HD
#define NSPLIT 8      // split-K factor
#define KCHUNK 256    // FAN / NSPLIT
#define BK   64
#define BM   32
#define BN   128
#define CAP  128      // max neighbors per (agent, cell); expected ~17, +5 sigma ~70

// ---------------- Kernel 1: social pooling ----------------
// one block per agent, 256 threads (4 waves). Wave w owns cells 4w..4w+3;
// running max lives in registers (float2 per lane = 2 of 128 h-values).
__global__ __launch_bounds__(256) void pool_kernel(
    const float* __restrict__ pos,
    const float* __restrict__ hidden,
    float* __restrict__ pooled /* [NA][FAN] */)
{
    __shared__ int lists[GG][CAP];   // per-cell compacted neighbor indices, 8 KB
    __shared__ int cnt[GG];

    const int i = blockIdx.x;
    const int t = threadIdx.x;
    if (t < GG) cnt[t] = 0;
    __syncthreads();

    const float px = pos[2 * i], py = pos[2 * i + 1];

    // Pass A: classify every j, append to its cell's list.
    // NaN/inf positions propagate into dx/dy and fail the <= compares,
    // matching the reference's finite-pos masking.
    for (int j = t; j < NA; j += 256) {
        float dx = pos[2 * j]     - px;
        float dy = pos[2 * j + 1] - py;
        bool inbox = (fabsf(dx) <= 1.0f) && (fabsf(dy) <= 1.0f) && (j != i);
        if (inbox) {
            int gx = min(max((int)floorf((dx + 1.0f) * 2.0f), 0), 3);
            int gy = min(max((int)floorf((dy + 1.0f) * 2.0f), 0), 3);
            int c  = gx * 4 + gy;
            int slot = atomicAdd(&cnt[c], 1);
            if (slot < CAP) lists[c][slot] = j;
        }
    }
    __syncthreads();

    // Pass B: register-resident max, uniform inner loop, 4 loads in flight.
    const int w = t >> 6, lane = t & 63;
    const float2* __restrict__ hid2 = (const float2*)hidden;   // [NA][64]
    float* outrow = pooled + (size_t)i * FAN;

    #pragma unroll
    for (int q = 0; q < 4; ++q) {
        const int c = w * 4 + q;
        const int n = min(cnt[c], CAP);
        const int* lst = lists[c];
        float2 r = make_float2(-INFINITY, -INFINITY);
        int k = 0;
        for (; k + 4 <= n; k += 4) {
            int j0 = lst[k], j1 = lst[k + 1], j2 = lst[k + 2], j3 = lst[k + 3];
            float2 v0 = hid2[j0 * 64 + lane];
            float2 v1 = hid2[j1 * 64 + lane];
            float2 v2 = hid2[j2 * 64 + lane];
            float2 v3 = hid2[j3 * 64 + lane];
            r.x = fmaxf(fmaxf(fmaxf(v0.x, v1.x), fmaxf(v2.x, v3.x)), r.x);
            r.y = fmaxf(fmaxf(fmaxf(v0.y, v1.y), fmaxf(v2.y, v3.y)), r.y);
        }
        for (; k < n; ++k) {
            float2 v = hid2[lst[k] * 64 + lane];
            r.x = fmaxf(r.x, v.x);
            r.y = fmaxf(r.y, v.y);
        }
        if (n == 0) { r.x = 0.0f; r.y = 0.0f; }   // empty cell -> zeros (cnt>0 semantics)
        *(float2*)(outrow + c * HD + lane * 2) = r;
    }
}

// ---------------- Kernel 2: fp32 tiled GEMM with split-K ----------------
// C_partial[kc][i][p] = sum_{k in chunk kc} pooled[i][k] * W[p][k]
__global__ __launch_bounds__(256) void gemm_kernel(
    const float* __restrict__ A,   // [NA][FAN]
    const float* __restrict__ W,   // [PD][FAN]
    float* __restrict__ part)      // [NSPLIT][NA][PD]
{
    __shared__ float As[BK][BM + 1];  // [k][m], +1 pad kills store conflicts
    __shared__ float Bs[BK][BN];      // [k][p]

    const int mt = blockIdx.x;        // 0..31
    const int kc = blockIdx.y;        // 0..7
    const int t  = threadIdx.x;
    const int m0 = mt * BM;
    const int k0 = kc * KCHUNK;
    const int tn = t & 31, tm = t >> 5;   // tn: 0..31 (p/4), tm: 0..7 (m/4)

    float acc[4][4] = {};

    for (int kt = 0; kt < KCHUNK; kt += BK) {
        // stage A tile (32 rows x 64 k), transposed into As[k][m]
        {
            const int row = t >> 3;           // 0..31
            const int kk  = (t & 7) * 8;      // 0..56
            const float4* src = (const float4*)(A + (size_t)(m0 + row) * FAN + k0 + kt + kk);
            #pragma unroll
            for (int u = 0; u < 2; ++u) {
                float4 v = src[u];
                As[kk + 4 * u + 0][row] = v.x;
                As[kk + 4 * u + 1][row] = v.y;
                As[kk + 4 * u + 2][row] = v.z;
                As[kk + 4 * u + 3][row] = v.w;
            }
        }
        // stage B tile (128 rows x 64 k), transposed into Bs[k][p]
        {
            const int row = t >> 1;           // 0..127
            const int kk  = (t & 1) * 32;     // 0 or 32
            const float4* src = (const float4*)(W + (size_t)row * FAN + k0 + kt + kk);
            #pragma unroll
            for (int u = 0; u < 8; ++u) {
                float4 v = src[u];
                Bs[kk + 4 * u + 0][row] = v.x;
                Bs[kk + 4 * u + 1][row] = v.y;
                Bs[kk + 4 * u + 2][row] = v.z;
                Bs[kk + 4 * u + 3][row] = v.w;
            }
        }
        __syncthreads();

        #pragma unroll 8
        for (int kk = 0; kk < BK; ++kk) {
            float a0 = As[kk][tm * 4 + 0];
            float a1 = As[kk][tm * 4 + 1];
            float a2 = As[kk][tm * 4 + 2];
            float a3 = As[kk][tm * 4 + 3];
            float4 bv = *(const float4*)&Bs[kk][tn * 4];
            acc[0][0] = fmaf(a0, bv.x, acc[0][0]);
            acc[0][1] = fmaf(a0, bv.y, acc[0][1]);
            acc[0][2] = fmaf(a0, bv.z, acc[0][2]);
            acc[0][3] = fmaf(a0, bv.w, acc[0][3]);
            acc[1][0] = fmaf(a1, bv.x, acc[1][0]);
            acc[1][1] = fmaf(a1, bv.y, acc[1][1]);
            acc[1][2] = fmaf(a1, bv.z, acc[1][2]);
            acc[1][3] = fmaf(a1, bv.w, acc[1][3]);
            acc[2][0] = fmaf(a2, bv.x, acc[2][0]);
            acc[2][1] = fmaf(a2, bv.y, acc[2][1]);
            acc[2][2] = fmaf(a2, bv.z, acc[2][2]);
            acc[2][3] = fmaf(a2, bv.w, acc[2][3]);
            acc[3][0] = fmaf(a3, bv.x, acc[3][0]);
            acc[3][1] = fmaf(a3, bv.y, acc[3][1]);
            acc[3][2] = fmaf(a3, bv.z, acc[3][2]);
            acc[3][3] = fmaf(a3, bv.w, acc[3][3]);
        }
        __syncthreads();
    }

    #pragma unroll
    for (int mm = 0; mm < 4; ++mm) {
        float4 v = make_float4(acc[mm][0], acc[mm][1], acc[mm][2], acc[mm][3]);
        *(float4*)(part + ((size_t)kc * NA + m0 + tm * 4 + mm) * PD + tn * 4) = v;
    }
}

// ---------------- Kernel 3: reduce partials + bias + relu ----------------
__global__ __launch_bounds__(256) void finish_kernel(
    const float* __restrict__ part,
    const float* __restrict__ bias,
    float* __restrict__ out)
{
    const int g = blockIdx.x * 256 + threadIdx.x;  // 0..NA*PD-1
    float s = bias[g & (PD - 1)];
    #pragma unroll
    for (int c = 0; c < NSPLIT; ++c)
        s += part[(size_t)c * NA * PD + g];
    out[g] = fmaxf(s, 0.0f);
}

extern "C" void kernel_launch(void* const* d_in, const int* in_sizes, int n_in,
                              void* d_out, int out_size, void* d_ws, size_t ws_size,
                              hipStream_t stream)
{
    const float* pos    = (const float*)d_in[0];
    const float* hidden = (const float*)d_in[1];
    const float* W      = (const float*)d_in[2];
    const float* b      = (const float*)d_in[3];
    float* out = (float*)d_out;

    float* pooled = (float*)d_ws;                   // NA*FAN f32 = 8 MiB
    float* part   = pooled + (size_t)NA * FAN;      // NSPLIT*NA*PD f32 = 4 MiB

    pool_kernel<<<NA, 256, 0, stream>>>(pos, hidden, pooled);
    gemm_kernel<<<dim3(NA / BM, NSPLIT), 256, 0, stream>>>(pooled, W, part);
    finish_kernel<<<(NA * PD) / 256, 256, 0, stream>>>(part, b, out);
}

// Round 4
// 85.702 us; speedup vs baseline: 1.3492x; 1.1392x over previous
//
#include <hip/hip_runtime.h>
#include <math.h>

#define NA   1024     // num agents
#define HD   128      // hidden dim
#define GG   16       // G*G cells
#define PD   128      // pool (output) dim
#define FAN  2048     // GG*HD
#define KS   8        // split-K factor
#define KC   256      // FAN / KS
#define CAP  128      // max neighbors per (agent, cell); mean ~17, CAP=128 is +14 sigma

typedef float  f32x4  __attribute__((ext_vector_type(4)));
typedef short  bf16x8 __attribute__((ext_vector_type(8)));
typedef unsigned short ushort_t;
typedef unsigned int   uint_t;

// RNE float -> bf16 (matches hardware convert for finite values)
static __device__ __forceinline__ ushort_t f2bf(float f) {
    uint_t u = __float_as_uint(f);
    u += 0x7fffu + ((u >> 16) & 1u);
    return (ushort_t)(u >> 16);
}

// ---------------- Kernel 1: social pooling (bf16 out) + W->bf16 convert ----
// one block per agent, 256 threads (4 waves). Wave w owns cells 4w..4w+3;
// running max lives in registers (float2 per lane = 2 of 128 h-values).
__global__ __launch_bounds__(256) void pool_kernel(
    const float* __restrict__ pos,
    const float* __restrict__ hidden,
    const float* __restrict__ W,
    ushort_t*    __restrict__ Wbf,     // [PD][FAN] bf16
    uint_t*      __restrict__ pooledu) // [NA][FAN/2] packed bf16x2
{
    __shared__ int lists[GG][CAP];   // per-cell compacted neighbor indices, 8 KB
    __shared__ int cnt[GG];

    const int i = blockIdx.x;
    const int t = threadIdx.x;

    // W -> bf16 conversion, spread over the whole grid (1024*256 == PD*FAN)
    {
        const int e = i * 256 + t;
        Wbf[e] = f2bf(W[e]);
    }

    if (t < GG) cnt[t] = 0;
    __syncthreads();

    const float px = pos[2 * i], py = pos[2 * i + 1];

    // Pass A: classify every j, append to its cell's list.
    // NaN/inf positions propagate into dx/dy and fail the <= compares,
    // matching the reference's finite-pos masking.
    for (int j = t; j < NA; j += 256) {
        float dx = pos[2 * j]     - px;
        float dy = pos[2 * j + 1] - py;
        bool inbox = (fabsf(dx) <= 1.0f) && (fabsf(dy) <= 1.0f) && (j != i);
        if (inbox) {
            int gx = min(max((int)floorf((dx + 1.0f) * 2.0f), 0), 3);
            int gy = min(max((int)floorf((dy + 1.0f) * 2.0f), 0), 3);
            int c  = gx * 4 + gy;
            int slot = atomicAdd(&cnt[c], 1);
            if (slot < CAP) lists[c][slot] = j;
        }
    }
    __syncthreads();

    // Pass B: register-resident max, uniform inner loop, 4 loads in flight.
    const int w = t >> 6, lane = t & 63;
    const float2* __restrict__ hid2 = (const float2*)hidden;   // [NA][64]
    uint_t* outrow = pooledu + (size_t)i * (FAN / 2);

    #pragma unroll
    for (int q = 0; q < 4; ++q) {
        const int c = w * 4 + q;
        const int n = min(cnt[c], CAP);
        const int* lst = lists[c];
        float2 r = make_float2(-INFINITY, -INFINITY);
        int k = 0;
        for (; k + 4 <= n; k += 4) {
            int j0 = lst[k], j1 = lst[k + 1], j2 = lst[k + 2], j3 = lst[k + 3];
            float2 v0 = hid2[j0 * 64 + lane];
            float2 v1 = hid2[j1 * 64 + lane];
            float2 v2 = hid2[j2 * 64 + lane];
            float2 v3 = hid2[j3 * 64 + lane];
            r.x = fmaxf(fmaxf(fmaxf(v0.x, v1.x), fmaxf(v2.x, v3.x)), r.x);
            r.y = fmaxf(fmaxf(fmaxf(v0.y, v1.y), fmaxf(v2.y, v3.y)), r.y);
        }
        for (; k < n; ++k) {
            float2 v = hid2[lst[k] * 64 + lane];
            r.x = fmaxf(r.x, v.x);
            r.y = fmaxf(r.y, v.y);
        }
        if (n == 0) { r.x = 0.0f; r.y = 0.0f; }   // empty cell -> zeros (cnt>0 semantics)
        // pack 2 bf16 (h = 2*lane low, 2*lane+1 high)
        outrow[c * 64 + lane] = (uint_t)f2bf(r.x) | ((uint_t)f2bf(r.y) << 16);
    }
}

// ---------------- Kernel 2: bf16 MFMA GEMM, zero-LDS, split-K -------------
// part[ks][m][p] = sum_{k in chunk ks} pooled[m][k] * W[p][k]
// Per wave: 16x32 output tile. Fragments straight from global (L2-resident).
// A-frag/B-frag layout (16x16x32): lane l -> row (l&15), k = (l>>4)*8 + j.
// D layout (m89-verified): col = lane&15, row = (lane>>4)*4 + reg.
__global__ __launch_bounds__(256) void gemm_kernel(
    const ushort_t* __restrict__ Abf,  // pooled [NA][FAN] bf16
    const ushort_t* __restrict__ Wbf,  // [PD][FAN] bf16
    float* __restrict__ part)          // [KS][NA][PD]
{
    const int mt = blockIdx.x;    // 0..63
    const int ks = blockIdx.y;    // 0..7
    const int w  = threadIdx.x >> 6;
    const int l  = threadIdx.x & 63;
    const int m0 = mt * 16;
    const int k0 = ks * KC;
    const int n0 = w * 32;

    const int lm = l & 15;          // m (for A) / n (for B)
    const int kg = (l >> 4) * 8;    // k-offset within the 32-wide step

    const ushort_t* aptr  = Abf + (size_t)(m0 + lm) * FAN + k0 + kg;
    const ushort_t* bptr0 = Wbf + (size_t)(n0 + lm) * FAN + k0 + kg;
    const ushort_t* bptr1 = bptr0 + 16 * FAN;

    f32x4 acc0 = {0.f, 0.f, 0.f, 0.f};
    f32x4 acc1 = {0.f, 0.f, 0.f, 0.f};

    #pragma unroll
    for (int kt = 0; kt < KC; kt += 32) {
        bf16x8 a  = *(const bf16x8*)(aptr  + kt);
        bf16x8 b0 = *(const bf16x8*)(bptr0 + kt);
        bf16x8 b1 = *(const bf16x8*)(bptr1 + kt);
        acc0 = __builtin_amdgcn_mfma_f32_16x16x32_bf16(a, b0, acc0, 0, 0, 0);
        acc1 = __builtin_amdgcn_mfma_f32_16x16x32_bf16(a, b1, acc1, 0, 0, 0);
    }

    const int row0 = (l >> 4) * 4;
    float* p0 = part + ((size_t)ks * NA + m0) * PD + n0;
    #pragma unroll
    for (int r = 0; r < 4; ++r) {
        p0[(row0 + r) * PD + lm]      = acc0[r];
        p0[(row0 + r) * PD + 16 + lm] = acc1[r];
    }
}

// ---------------- Kernel 3: reduce partials + bias + relu ----------------
__global__ __launch_bounds__(256) void finish_kernel(
    const float* __restrict__ part,
    const float* __restrict__ bias,
    float* __restrict__ out)
{
    const int g = blockIdx.x * 256 + threadIdx.x;  // 0..NA*PD-1
    float s = bias[g & (PD - 1)];
    #pragma unroll
    for (int c = 0; c < KS; ++c)
        s += part[(size_t)c * NA * PD + g];
    out[g] = fmaxf(s, 0.0f);
}

extern "C" void kernel_launch(void* const* d_in, const int* in_sizes, int n_in,
                              void* d_out, int out_size, void* d_ws, size_t ws_size,
                              hipStream_t stream)
{
    const float* pos    = (const float*)d_in[0];
    const float* hidden = (const float*)d_in[1];
    const float* W      = (const float*)d_in[2];
    const float* b      = (const float*)d_in[3];
    float* out = (float*)d_out;

    ushort_t* Wbf     = (ushort_t*)d_ws;                        // 512 KB
    ushort_t* pooled  = Wbf + (size_t)PD * FAN;                 // 4 MB bf16
    float*    part    = (float*)(pooled + (size_t)NA * FAN);    // 4 MB f32

    pool_kernel<<<NA, 256, 0, stream>>>(pos, hidden, W, Wbf, (uint_t*)pooled);
    gemm_kernel<<<dim3(NA / 16, KS), 256, 0, stream>>>(pooled, Wbf, part);
    finish_kernel<<<(NA * PD) / 256, 256, 0, stream>>>(part, b, out);
}